// Round 1
// baseline (7208.442 us; speedup 1.0000x reference)
//
#include <hip/hip_runtime.h>

// SSN RK4 integrator: 19 intervals x 2 substeps x 4 RK stages = 152 fused GEMV kernels.
// Each stage kernel: y = W @ v + h; k = relu(y)^2 - v; RK4 epilogue per stage.
// N = 8192, W = 8192x8192 fp32 (256 MiB) -> streaming memory bound.

#define NTOT 8192
#define LSTEPS 20
#define ROWS_PER_BLOCK 8   // 4 waves x 2 rows
#define NBLOCKS (NTOT / ROWS_PER_BLOCK)

__global__ void compute_dts_kernel(const float* __restrict__ t, float* __restrict__ dts) {
    int i = threadIdx.x;
    if (i < LSTEPS - 1) dts[i] = t[i + 1] - t[i];
}

// STAGE: 1..4 of RK4.
// dst = v_next for stages 1-3; dst = r_next for stage 4.
template<int STAGE>
__global__ __launch_bounds__(256) void ssn_stage(
    const float* __restrict__ W,
    const float* __restrict__ v_in,
    const float* __restrict__ hvec,
    const float* __restrict__ r_base,
    float* __restrict__ acc,
    float* __restrict__ dst,
    float* __restrict__ out_slice,   // stage 4 only; may be null
    const float* __restrict__ dts, int dt_idx)
{
    __shared__ float v_lds[NTOT];    // 32 KB
    {
        float4* l4 = reinterpret_cast<float4*>(v_lds);
        const float4* v4 = reinterpret_cast<const float4*>(v_in);
        for (int i = threadIdx.x; i < NTOT / 4; i += 256) l4[i] = v4[i];
    }
    __syncthreads();

    const int wave = threadIdx.x >> 6;
    const int lane = threadIdx.x & 63;
    const int row0 = blockIdx.x * ROWS_PER_BLOCK + wave * 2;

    const float4* __restrict__ w0 = reinterpret_cast<const float4*>(W + (size_t)row0 * NTOT);
    const float4* __restrict__ w1 = reinterpret_cast<const float4*>(W + (size_t)(row0 + 1) * NTOT);
    const float4* __restrict__ l4 = reinterpret_cast<const float4*>(v_lds);

    float s0 = 0.f, s1 = 0.f;
    #pragma unroll 8
    for (int it = 0; it < NTOT / 256; ++it) {   // 32 iters, 16B/lane/row
        float4 vv = l4[it * 64 + lane];
        float4 a  = w0[it * 64 + lane];
        float4 b  = w1[it * 64 + lane];
        s0 += a.x * vv.x + a.y * vv.y + a.z * vv.z + a.w * vv.w;
        s1 += b.x * vv.x + b.y * vv.y + b.z * vv.z + b.w * vv.w;
    }
    #pragma unroll
    for (int off = 32; off > 0; off >>= 1) {
        s0 += __shfl_down(s0, off);
        s1 += __shfl_down(s1, off);
    }

    if (lane == 0) {
        const float ds = dts[dt_idx] * 0.5f;   // dt / SUBSTEPS
        #pragma unroll
        for (int rr = 0; rr < 2; ++rr) {
            const int row = row0 + rr;
            float y  = (rr ? s1 : s0) + hvec[row];
            float rl = fmaxf(y, 0.f);
            float k  = rl * rl - v_lds[row];     // _drdt at this stage point
            if (STAGE == 1) {
                acc[row] = k;
                dst[row] = r_base[row] + 0.5f * ds * k;
            } else if (STAGE == 2) {
                acc[row] += 2.f * k;
                dst[row] = r_base[row] + 0.5f * ds * k;
            } else if (STAGE == 3) {
                acc[row] += 2.f * k;
                dst[row] = r_base[row] + ds * k;
            } else {
                float a  = acc[row] + k;
                float rn = r_base[row] + (ds / 6.f) * a;
                dst[row] = rn;
                if (out_slice) out_slice[row] = rn;
            }
        }
    }
}

extern "C" void kernel_launch(void* const* d_in, const int* in_sizes, int n_in,
                              void* d_out, int out_size, void* d_ws, size_t ws_size,
                              hipStream_t stream) {
    (void)in_sizes; (void)n_in; (void)out_size; (void)ws_size;

    const float* W  = (const float*)d_in[0];
    const float* h  = (const float*)d_in[1];
    const float* r0 = (const float*)d_in[2];
    const float* t  = (const float*)d_in[3];
    float* out = (float*)d_out;

    float* ws  = (float*)d_ws;
    float* dts = ws;                  // 32 floats (19 used)
    float* rA  = ws + 32;
    float* rB  = rA + NTOT;
    float* vA  = rB + NTOT;
    float* vB  = vA + NTOT;
    float* acc = vB + NTOT;

    compute_dts_kernel<<<1, 32, 0, stream>>>(t, dts);

    // out[0] = r0
    hipMemcpyAsync(out, r0, NTOT * sizeof(float), hipMemcpyDeviceToDevice, stream);

    const float* r_in = r0;
    float* r_out = rA;
    dim3 grid(NBLOCKS), block(256);

    for (int l = 0; l < LSTEPS - 1; ++l) {
        for (int s = 0; s < 2; ++s) {
            float* out_slice = (s == 1) ? (out + (size_t)(l + 1) * NTOT) : nullptr;
            ssn_stage<1><<<grid, block, 0, stream>>>(W, r_in, h, r_in, acc, vA, nullptr, dts, l);
            ssn_stage<2><<<grid, block, 0, stream>>>(W, vA,   h, r_in, acc, vB, nullptr, dts, l);
            ssn_stage<3><<<grid, block, 0, stream>>>(W, vB,   h, r_in, acc, vA, nullptr, dts, l);
            ssn_stage<4><<<grid, block, 0, stream>>>(W, vA,   h, r_in, acc, r_out, out_slice, dts, l);
            r_in  = r_out;
            r_out = (r_out == rA) ? rB : rA;
        }
    }
}

// Round 3
// 3758.041 us; speedup vs baseline: 1.9181x; 1.9181x over previous
//
#include <hip/hip_runtime.h>

// SSN RK4 integrator, bf16-W variant.
// W (8192^2 fp32, 256 MiB) is converted once per call to bf16 (128 MiB) in d_ws.
// 128 MiB is L3-resident on MI355X (256 MiB Infinity Cache), so the 152
// sequential GEMV stages stream W from L3 instead of HBM, and at half the bytes.
// r / v / h / accumulators stay fp32 (accuracy: bf16 W rounding -> ~1e-4 absmax).

#define NTOT 8192
#define LSTEPS 20
#define ROWS_PER_BLOCK 8   // 4 waves x 2 rows
#define NBLOCKS (NTOT / ROWS_PER_BLOCK)

__global__ void compute_dts_kernel(const float* __restrict__ t, float* __restrict__ dts) {
    int i = threadIdx.x;
    if (i < LSTEPS - 1) dts[i] = t[i + 1] - t[i];
}

__device__ __forceinline__ unsigned short f2b_rne(float f) {
    unsigned u = __float_as_uint(f);
    unsigned r = ((u >> 16) & 1u) + 0x7fffu;   // round-to-nearest-even
    return (unsigned short)((u + r) >> 16);
}
__device__ __forceinline__ float b_lo(unsigned u) { return __uint_as_float(u << 16); }
__device__ __forceinline__ float b_hi(unsigned u) { return __uint_as_float(u & 0xffff0000u); }

// W fp32 -> bf16 packed. Each iteration: 8 floats in (32B), uint4 out (16B).
__global__ __launch_bounds__(256) void convert_w_bf16(const float* __restrict__ W,
                                                      uint4* __restrict__ Wb) {
    const size_t n8 = (size_t)NTOT * NTOT / 8;
    size_t idx = (size_t)blockIdx.x * blockDim.x + threadIdx.x;
    size_t stride = (size_t)gridDim.x * blockDim.x;
    const float4* W4 = (const float4*)W;
    for (size_t i = idx; i < n8; i += stride) {
        float4 a = W4[2 * i], b = W4[2 * i + 1];
        uint4 o;
        o.x = (unsigned)f2b_rne(a.x) | ((unsigned)f2b_rne(a.y) << 16);
        o.y = (unsigned)f2b_rne(a.z) | ((unsigned)f2b_rne(a.w) << 16);
        o.z = (unsigned)f2b_rne(b.x) | ((unsigned)f2b_rne(b.y) << 16);
        o.w = (unsigned)f2b_rne(b.z) | ((unsigned)f2b_rne(b.w) << 16);
        Wb[i] = o;
    }
}

// STAGE 1..4 of RK4. dst = v_next (stages 1-3) or r_next (stage 4).
template<int STAGE>
__global__ __launch_bounds__(256) void ssn_stage(
    const unsigned short* __restrict__ Wb,
    const float* __restrict__ v_in,
    const float* __restrict__ hvec,
    const float* __restrict__ r_base,
    float* __restrict__ acc,
    float* __restrict__ dst,
    float* __restrict__ out_slice,   // stage 4 only; may be null
    const float* __restrict__ dts, int dt_idx)
{
    __shared__ float v_lds[NTOT];    // 32 KB, fp32 v
    {
        float4* l4w = reinterpret_cast<float4*>(v_lds);
        const float4* v4 = reinterpret_cast<const float4*>(v_in);
        for (int i = threadIdx.x; i < NTOT / 4; i += 256) l4w[i] = v4[i];
    }
    __syncthreads();

    const int wave = threadIdx.x >> 6;
    const int lane = threadIdx.x & 63;
    const int row0 = blockIdx.x * ROWS_PER_BLOCK + wave * 2;

    const uint4* __restrict__ w0 = reinterpret_cast<const uint4*>(Wb + (size_t)row0 * NTOT);
    const uint4* __restrict__ w1 = reinterpret_cast<const uint4*>(Wb + (size_t)(row0 + 1) * NTOT);
    const float4* __restrict__ l4 = reinterpret_cast<const float4*>(v_lds);

    float s0 = 0.f, s1 = 0.f;
    #pragma unroll
    for (int it = 0; it < 16; ++it) {        // 8 bf16/lane/row per iter
        uint4 a = w0[it * 64 + lane];
        uint4 b = w1[it * 64 + lane];
        float4 p = l4[it * 128 + lane * 2];
        float4 q = l4[it * 128 + lane * 2 + 1];
        s0 += b_lo(a.x) * p.x + b_hi(a.x) * p.y + b_lo(a.y) * p.z + b_hi(a.y) * p.w
            + b_lo(a.z) * q.x + b_hi(a.z) * q.y + b_lo(a.w) * q.z + b_hi(a.w) * q.w;
        s1 += b_lo(b.x) * p.x + b_hi(b.x) * p.y + b_lo(b.y) * p.z + b_hi(b.y) * p.w
            + b_lo(b.z) * q.x + b_hi(b.z) * q.y + b_lo(b.w) * q.z + b_hi(b.w) * q.w;
    }
    #pragma unroll
    for (int off = 32; off > 0; off >>= 1) {
        s0 += __shfl_down(s0, off);
        s1 += __shfl_down(s1, off);
    }

    if (lane == 0) {
        const float ds = dts[dt_idx] * 0.5f;   // dt / SUBSTEPS
        #pragma unroll
        for (int rr = 0; rr < 2; ++rr) {
            const int row = row0 + rr;
            float y  = (rr ? s1 : s0) + hvec[row];
            float rl = fmaxf(y, 0.f);
            float k  = rl * rl - v_lds[row];
            if (STAGE == 1) {
                acc[row] = k;
                dst[row] = r_base[row] + 0.5f * ds * k;
            } else if (STAGE == 2) {
                acc[row] += 2.f * k;
                dst[row] = r_base[row] + 0.5f * ds * k;
            } else if (STAGE == 3) {
                acc[row] += 2.f * k;
                dst[row] = r_base[row] + ds * k;
            } else {
                float a  = acc[row] + k;
                float rn = r_base[row] + (ds / 6.f) * a;
                dst[row] = rn;
                if (out_slice) out_slice[row] = rn;
            }
        }
    }
}

extern "C" void kernel_launch(void* const* d_in, const int* in_sizes, int n_in,
                              void* d_out, int out_size, void* d_ws, size_t ws_size,
                              hipStream_t stream) {
    (void)in_sizes; (void)n_in; (void)out_size; (void)ws_size;

    const float* W  = (const float*)d_in[0];
    const float* h  = (const float*)d_in[1];
    const float* r0 = (const float*)d_in[2];
    const float* t  = (const float*)d_in[3];
    float* out = (float*)d_out;

    float* ws  = (float*)d_ws;
    float* dts = ws;                  // 32 floats (19 used)
    float* rA  = ws + 32;
    float* rB  = rA + NTOT;
    float* vA  = rB + NTOT;
    float* vB  = vA + NTOT;
    float* acc = vB + NTOT;
    // bf16 W at 4 MiB offset into ws (needs 128 MiB; ws is ~1 GiB)
    unsigned short* Wb = (unsigned short*)((char*)d_ws + (4u << 20));

    compute_dts_kernel<<<1, 32, 0, stream>>>(t, dts);
    convert_w_bf16<<<2048, 256, 0, stream>>>(W, (uint4*)Wb);

    // out[0] = r0
    hipMemcpyAsync(out, r0, NTOT * sizeof(float), hipMemcpyDeviceToDevice, stream);

    const float* r_in = r0;
    float* r_out = rA;
    dim3 grid(NBLOCKS), block(256);

    for (int l = 0; l < LSTEPS - 1; ++l) {
        for (int s = 0; s < 2; ++s) {
            float* out_slice = (s == 1) ? (out + (size_t)(l + 1) * NTOT) : nullptr;
            ssn_stage<1><<<grid, block, 0, stream>>>(Wb, r_in, h, r_in, acc, vA, nullptr, dts, l);
            ssn_stage<2><<<grid, block, 0, stream>>>(Wb, vA,   h, r_in, acc, vB, nullptr, dts, l);
            ssn_stage<3><<<grid, block, 0, stream>>>(Wb, vB,   h, r_in, acc, vA, nullptr, dts, l);
            ssn_stage<4><<<grid, block, 0, stream>>>(Wb, vA,   h, r_in, acc, r_out, out_slice, dts, l);
            r_in  = r_out;
            r_out = (r_out == rA) ? rB : rA;
        }
    }
}

// Round 4
// 3479.191 us; speedup vs baseline: 2.0719x; 1.0801x over previous
//
#include <hip/hip_runtime.h>

// SSN RK4 integrator, bf16-W, cache-served v (no LDS staging).
// W (8192^2 fp32, 256 MiB) converted once per call to bf16 (128 MiB) in d_ws.
// 152 sequential fused GEMV stages stream W at memory-system rate; v (32 KB)
// is read through L1/L2 per iteration, overlapping the W stream instead of
// serializing 5 us of LDS preload per stage.

#define NTOT 8192
#define LSTEPS 20
#define ROWS_PER_BLOCK 8   // 4 waves x 2 rows
#define NBLOCKS (NTOT / ROWS_PER_BLOCK)

__global__ void compute_dts_kernel(const float* __restrict__ t, float* __restrict__ dts) {
    int i = threadIdx.x;
    if (i < LSTEPS - 1) dts[i] = t[i + 1] - t[i];
}

__device__ __forceinline__ unsigned short f2b_rne(float f) {
    unsigned u = __float_as_uint(f);
    unsigned r = ((u >> 16) & 1u) + 0x7fffu;   // round-to-nearest-even
    return (unsigned short)((u + r) >> 16);
}
__device__ __forceinline__ float b_lo(unsigned u) { return __uint_as_float(u << 16); }
__device__ __forceinline__ float b_hi(unsigned u) { return __uint_as_float(u & 0xffff0000u); }

// W fp32 -> bf16 packed. Each iteration: 8 floats in (32B), uint4 out (16B).
__global__ __launch_bounds__(256) void convert_w_bf16(const float* __restrict__ W,
                                                      uint4* __restrict__ Wb) {
    const size_t n8 = (size_t)NTOT * NTOT / 8;
    size_t idx = (size_t)blockIdx.x * blockDim.x + threadIdx.x;
    size_t stride = (size_t)gridDim.x * blockDim.x;
    const float4* W4 = (const float4*)W;
    for (size_t i = idx; i < n8; i += stride) {
        float4 a = W4[2 * i], b = W4[2 * i + 1];
        uint4 o;
        o.x = (unsigned)f2b_rne(a.x) | ((unsigned)f2b_rne(a.y) << 16);
        o.y = (unsigned)f2b_rne(a.z) | ((unsigned)f2b_rne(a.w) << 16);
        o.z = (unsigned)f2b_rne(b.x) | ((unsigned)f2b_rne(b.y) << 16);
        o.w = (unsigned)f2b_rne(b.z) | ((unsigned)f2b_rne(b.w) << 16);
        Wb[i] = o;
    }
}

// STAGE 1..4 of RK4. dst = v_next (stages 1-3) or r_next (stage 4).
template<int STAGE>
__global__ __launch_bounds__(256) void ssn_stage(
    const unsigned short* __restrict__ Wb,
    const float* __restrict__ v_in,
    const float* __restrict__ hvec,
    const float* __restrict__ r_base,
    float* __restrict__ acc,
    float* __restrict__ dst,
    float* __restrict__ out_slice,   // stage 4 only; may be null
    const float* __restrict__ dts, int dt_idx)
{
    const int wave = threadIdx.x >> 6;
    const int lane = threadIdx.x & 63;
    const int row0 = blockIdx.x * ROWS_PER_BLOCK + wave * 2;

    const uint4* __restrict__ w0 = reinterpret_cast<const uint4*>(Wb + (size_t)row0 * NTOT);
    const uint4* __restrict__ w1 = reinterpret_cast<const uint4*>(Wb + (size_t)(row0 + 1) * NTOT);
    const float4* __restrict__ v4 = reinterpret_cast<const float4*>(v_in);

    float s0 = 0.f, s1 = 0.f;
    #pragma unroll
    for (int it = 0; it < 16; ++it) {        // 8 bf16/lane/row per iter
        uint4 a = w0[it * 64 + lane];
        uint4 b = w1[it * 64 + lane];
        float4 p = v4[it * 128 + lane * 2];
        float4 q = v4[it * 128 + lane * 2 + 1];
        s0 += b_lo(a.x) * p.x + b_hi(a.x) * p.y + b_lo(a.y) * p.z + b_hi(a.y) * p.w
            + b_lo(a.z) * q.x + b_hi(a.z) * q.y + b_lo(a.w) * q.z + b_hi(a.w) * q.w;
        s1 += b_lo(b.x) * p.x + b_hi(b.x) * p.y + b_lo(b.y) * p.z + b_hi(b.y) * p.w
            + b_lo(b.z) * q.x + b_hi(b.z) * q.y + b_lo(b.w) * q.z + b_hi(b.w) * q.w;
    }
    #pragma unroll
    for (int off = 32; off > 0; off >>= 1) {
        s0 += __shfl_down(s0, off);
        s1 += __shfl_down(s1, off);
    }

    if (lane == 0) {
        const float ds = dts[dt_idx] * 0.5f;   // dt / SUBSTEPS
        #pragma unroll
        for (int rr = 0; rr < 2; ++rr) {
            const int row = row0 + rr;
            float y  = (rr ? s1 : s0) + hvec[row];
            float rl = fmaxf(y, 0.f);
            float k  = rl * rl - v_in[row];
            if (STAGE == 1) {
                acc[row] = k;
                dst[row] = r_base[row] + 0.5f * ds * k;
            } else if (STAGE == 2) {
                acc[row] += 2.f * k;
                dst[row] = r_base[row] + 0.5f * ds * k;
            } else if (STAGE == 3) {
                acc[row] += 2.f * k;
                dst[row] = r_base[row] + ds * k;
            } else {
                float a  = acc[row] + k;
                float rn = r_base[row] + (ds / 6.f) * a;
                dst[row] = rn;
                if (out_slice) out_slice[row] = rn;
            }
        }
    }
}

extern "C" void kernel_launch(void* const* d_in, const int* in_sizes, int n_in,
                              void* d_out, int out_size, void* d_ws, size_t ws_size,
                              hipStream_t stream) {
    (void)in_sizes; (void)n_in; (void)out_size; (void)ws_size;

    const float* W  = (const float*)d_in[0];
    const float* h  = (const float*)d_in[1];
    const float* r0 = (const float*)d_in[2];
    const float* t  = (const float*)d_in[3];
    float* out = (float*)d_out;

    float* ws  = (float*)d_ws;
    float* dts = ws;                  // 32 floats (19 used)
    float* rA  = ws + 32;
    float* rB  = rA + NTOT;
    float* vA  = rB + NTOT;
    float* vB  = vA + NTOT;
    float* acc = vB + NTOT;
    // bf16 W at 4 MiB offset into ws (needs 128 MiB; ws is ~1 GiB)
    unsigned short* Wb = (unsigned short*)((char*)d_ws + (4u << 20));

    compute_dts_kernel<<<1, 32, 0, stream>>>(t, dts);
    convert_w_bf16<<<2048, 256, 0, stream>>>(W, (uint4*)Wb);

    // out[0] = r0
    hipMemcpyAsync(out, r0, NTOT * sizeof(float), hipMemcpyDeviceToDevice, stream);

    const float* r_in = r0;
    float* r_out = rA;
    dim3 grid(NBLOCKS), block(256);

    for (int l = 0; l < LSTEPS - 1; ++l) {
        for (int s = 0; s < 2; ++s) {
            float* out_slice = (s == 1) ? (out + (size_t)(l + 1) * NTOT) : nullptr;
            ssn_stage<1><<<grid, block, 0, stream>>>(Wb, r_in, h, r_in, acc, vA, nullptr, dts, l);
            ssn_stage<2><<<grid, block, 0, stream>>>(Wb, vA,   h, r_in, acc, vB, nullptr, dts, l);
            ssn_stage<3><<<grid, block, 0, stream>>>(Wb, vB,   h, r_in, acc, vA, nullptr, dts, l);
            ssn_stage<4><<<grid, block, 0, stream>>>(Wb, vA,   h, r_in, acc, r_out, out_slice, dts, l);
            r_in  = r_out;
            r_out = (r_out == rA) ? rB : rA;
        }
    }
}